// Round 6
// baseline (466.298 us; speedup 1.0000x reference)
//
#include <hip/hip_runtime.h>
#include <hip/hip_bf16.h>
#include <math.h>

#define BB   64
#define SS   512
#define NHH  4
#define DD   256
#define HH   256
#define LDH  264   // bf16 LDS row stride (halfwords); 528B = 16B-aligned

typedef __attribute__((ext_vector_type(8))) short  short8;
typedef __attribute__((ext_vector_type(4))) float  floatx4;

// ---------------------------------------------------------------------------
// ws layout (floats): see R4/R5. Unchanged offsets.
// ---------------------------------------------------------------------------
#define OFF_V2     0
#define OFF_CB1    256
#define OFF_C2     512
#define OFF_CKW    513
#define OFF_QW     768
#define OFF_WK1    1024
#define OFF_BKP    1280
#define OFF_VT     1536
#define OFF_RU     1792
#define OFF_WFUSE  67328
#define OFF_WKF    132864
#define OFF_PACK   198400
#define OFF_CH     263936

__device__ __forceinline__ unsigned short f2b(float f) {
  __hip_bfloat16 h = __float2bfloat16(f);
  return __builtin_bit_cast(unsigned short, h);
}
__device__ __forceinline__ float b2f(unsigned short u) {
  unsigned v = (unsigned)u << 16;
  return __builtin_bit_cast(float, v);
}

// ---------------------------------------------------------------------------
// initA: blocks 0..255: Wfuse = Wproj @ W1b ; 256: bkp ; 257: vtmp = Wq@w2
// ---------------------------------------------------------------------------
__global__ __launch_bounds__(256) void initA_kernel(
    const float* __restrict__ Wproj, const float* __restrict__ W1,
    const float* __restrict__ bk, const float* __restrict__ bproj,
    const float* __restrict__ Wq, const float* __restrict__ w_mlp,
    float* __restrict__ ws)
{
  int tid = threadIdx.x;
  int bx = blockIdx.x;
  const float* W1b = W1 + 256 * 256;
  if (bx < 256) {
    __shared__ float row[256];
    row[tid] = Wproj[bx * 256 + tid];
    __syncthreads();
    float acc = 0.f;
#pragma unroll 8
    for (int k = 0; k < 256; ++k)
      acc = fmaf(row[k], W1b[k * 256 + tid], acc);
    ws[OFF_WFUSE + bx * 256 + tid] = acc;
  } else if (bx == 256) {
    float acc = bproj[tid];
#pragma unroll 8
    for (int k = 0; k < 256; ++k)
      acc = fmaf(bk[k], Wproj[k * 256 + tid], acc);
    ws[OFF_BKP + tid] = acc;
  } else {
    const float4* Wq4 = (const float4*)(Wq + tid * 256);
    const float4* w24 = (const float4*)(w_mlp + 256);
    float a = 0.f;
    for (int k = 0; k < 64; ++k) {
      float4 wv = Wq4[k], xv = w24[k];
      a = fmaf(wv.x, xv.x, fmaf(wv.y, xv.y, fmaf(wv.z, xv.z, fmaf(wv.w, xv.w, a))));
    }
    ws[OFF_VT + tid] = a;
  }
}

// ---------------------------------------------------------------------------
// initB: blocks 0..255: Wkf = Wk@Wfuse ; 256: cb1 ; 257: v2,c2,ckw,qw ; 258: wk1
// ---------------------------------------------------------------------------
__global__ __launch_bounds__(256) void initB_kernel(
    const float* __restrict__ Wk, const float* __restrict__ W1,
    const float* __restrict__ b1, const float* __restrict__ W2,
    const float* __restrict__ b2, const float* __restrict__ bq,
    const float* __restrict__ bk, const float* __restrict__ w_mlp,
    float* __restrict__ ws)
{
  int tid = threadIdx.x;
  int bx = blockIdx.x;
  if (bx < 256) {
    __shared__ float row[256];
    row[tid] = Wk[bx * 256 + tid];
    __syncthreads();
    float acc = 0.f;
    const float* Wf = ws + OFF_WFUSE;
#pragma unroll 8
    for (int k = 0; k < 256; ++k)
      acc = fmaf(row[k], Wf[k * 256 + tid], acc);
    ws[OFF_WKF + bx * 256 + tid] = acc;
  } else if (bx == 256) {
    const float* W1b = W1 + 256 * 256;
    float acc = b1[tid];
#pragma unroll 8
    for (int k = 0; k < 256; ++k)
      acc = fmaf(ws[OFF_BKP + k], W1b[k * 256 + tid], acc);
    ws[OFF_CB1 + tid] = acc;
  } else if (bx == 257) {
    __shared__ float red[256];
    {
      const float4* W24 = (const float4*)(W2 + tid * 256);
      const float4* v4  = (const float4*)(ws + OFF_VT);
      float a = 0.f;
      for (int k = 0; k < 64; ++k) {
        float4 wv = W24[k], xv = v4[k];
        a = fmaf(wv.x, xv.x, fmaf(wv.y, xv.y, fmaf(wv.z, xv.z, fmaf(wv.w, xv.w, a))));
      }
      ws[OFF_V2 + tid] = a;
    }
    red[tid] = bq[tid] * w_mlp[256 + tid];
    __syncthreads();
    for (int s = 128; s; s >>= 1) { if (tid < s) red[tid] += red[tid + s]; __syncthreads(); }
    float s2 = red[0];
    __syncthreads();
    ws[OFF_QW + tid] = s2;
    red[tid] = b2[tid] * ws[OFF_VT + tid];
    __syncthreads();
    for (int s = 128; s; s >>= 1) { if (tid < s) red[tid] += red[tid + s]; __syncthreads(); }
    if (tid == 0) ws[OFF_C2] = red[0] + s2;
    __syncthreads();
    red[tid] = bk[tid] * w_mlp[tid];
    __syncthreads();
    for (int s = 128; s; s >>= 1) { if (tid < s) red[tid] += red[tid + s]; __syncthreads(); }
    if (tid == 0) ws[OFF_CKW] = red[0];
  } else {
    const float4* Wk4 = (const float4*)(Wk + tid * 256);
    const float4* w14 = (const float4*)(w_mlp);
    float a = 0.f;
    for (int k = 0; k < 64; ++k) {
      float4 wv = Wk4[k], xv = w14[k];
      a = fmaf(wv.x, xv.x, fmaf(wv.y, xv.y, fmaf(wv.z, xv.z, fmaf(wv.w, xv.w, a))));
    }
    ws[OFF_WK1 + tid] = a;
  }
}

// ---------------------------------------------------------------------------
// initC: pack Wkf (mat0, from ws fp32) and W1a (mat1) into MFMA B-frag bf16
// ---------------------------------------------------------------------------
__global__ __launch_bounds__(256) void initC_kernel(
    const float* __restrict__ W1, float* __restrict__ ws)
{
  int idx = blockIdx.x * 256 + threadIdx.x;   // 0..131071
  int mat = idx >> 16;
  int rem = idx & 65535;
  int j    = rem & 7;
  int lane = (rem >> 3) & 63;
  int ks   = (rem >> 9) & 7;
  int pan  = rem >> 12;
  int k = ks * 32 + ((lane >> 4) << 3) + j;
  int n = pan * 16 + (lane & 15);
  float v = (mat == 0) ? ws[OFF_WKF + k * 256 + n] : W1[k * 256 + n];
  ((unsigned short*)(ws + OFF_PACK))[idx] = f2b(v);
}

// ---------------------------------------------------------------------------
// 64x256 (K=256) bf16 MFMA GEMM, 4x B-reuse
// ---------------------------------------------------------------------------
__device__ __forceinline__ void mfma_gemm4(
    const unsigned short* A_lds, const short8* __restrict__ Bp,
    const float* __restrict__ bias, floatx4 acc[4][4], int l, int w)
{
  int col = l & 15, quad = l >> 4;
#pragma unroll
  for (int pp = 0; pp < 4; ++pp) {
    float bv = bias ? bias[(w * 4 + pp) * 16 + col] : 0.f;
#pragma unroll
    for (int mf = 0; mf < 4; ++mf)
      acc[mf][pp] = (floatx4){bv, bv, bv, bv};
  }
  const short8* Bb = Bp + (size_t)(w * 4) * 512 + l;
  short8 bb[3][4];
#pragma unroll
  for (int pp = 0; pp < 4; ++pp) bb[0][pp] = Bb[pp * 512];
#pragma unroll
  for (int pp = 0; pp < 4; ++pp) bb[1][pp] = Bb[pp * 512 + 64];
#pragma unroll
  for (int kb = 0; kb < 8; ++kb) {
    if (kb + 2 < 8) {
#pragma unroll
      for (int pp = 0; pp < 4; ++pp)
        bb[(kb + 2) % 3][pp] = Bb[pp * 512 + (kb + 2) * 64];
    }
    short8 aa[4];
#pragma unroll
    for (int mf = 0; mf < 4; ++mf)
      aa[mf] = *(const short8*)(A_lds + (mf * 16 + col) * LDH + kb * 32 + quad * 8);
#pragma unroll
    for (int mf = 0; mf < 4; ++mf)
#pragma unroll
      for (int pp = 0; pp < 4; ++pp)
        acc[mf][pp] = __builtin_amdgcn_mfma_f32_16x16x32_bf16(
            aa[mf], bb[kb % 3][pp], acc[mf][pp], 0, 0, 0);
  }
}

// acc -> bf16 LDS tile (each wave writes its own n-panels; barrier after)
__device__ __forceinline__ void acc_to_lds(
    unsigned short* D, const floatx4 acc[4][4], int l, int w)
{
  int col = l & 15, quad = l >> 4;
#pragma unroll
  for (int mf = 0; mf < 4; ++mf)
#pragma unroll
    for (int pp = 0; pp < 4; ++pp)
#pragma unroll
      for (int r = 0; r < 4; ++r)
        D[(mf * 16 + quad * 4 + r) * LDH + (w * 4 + pp) * 16 + col] = f2b(acc[mf][pp][r]);
}

// LDS bf16 tile -> global, coalesced 16B chunks; layout [t][b][head][256]
__device__ __forceinline__ void lds_to_global_bf16(
    const unsigned short* S, unsigned short* __restrict__ g, int b, int tt, int tid)
{
#pragma unroll
  for (int it = 0; it < 8; ++it) {
    int u8 = it * 256 + tid;        // 16B chunk id, 0..2047
    int r = u8 >> 5;                // row 0..63
    int c8 = u8 & 31;               // chunk within row
    int t = tt * 16 + (r >> 2), head = r & 3;
    float4 v = *(const float4*)&S[r * LDH + c8 * 8];
    *(float4*)&g[(((size_t)t * 64 + b) * 4 + head) * 256 + c8 * 8] = v;
  }
}

// ---------------------------------------------------------------------------
// pre: one block per (b, tt). Both GEMMs held in regs; coalesced LDS epilogue.
// ---------------------------------------------------------------------------
__global__ __launch_bounds__(256, 2) void pre_kernel(
    const float* __restrict__ x, const float* __restrict__ ws,
    float* __restrict__ kw_c, unsigned short* __restrict__ xw1_c,
    unsigned short* __restrict__ kpw_c, int t0)
{
  __shared__ float kwbuf[256];
  __shared__ __align__(16) unsigned short XS[64 * LDH];

  int b  = blockIdx.x & 63;
  int tt = blockIdx.x >> 6;
  int tid = threadIdx.x;
  int l = tid & 63, w = tid >> 6;

  const float4* xsrc = (const float4*)(x + (size_t)(b * SS + t0 + tt * 16) * NHH * DD);
#pragma unroll
  for (int i = 0; i < 16; ++i) {
    int f4 = i * 256 + tid;
    int r = f4 >> 6, c4 = f4 & 63;
    float4 v = xsrc[f4];
    ushort4 h;
    h.x = f2b(v.x); h.y = f2b(v.y); h.z = f2b(v.z); h.w = f2b(v.w);
    *(ushort4*)&XS[r * LDH + c4 * 4] = h;
  }
  __syncthreads();

  const short8* wp0 = (const short8*)((const unsigned short*)(ws + OFF_PACK));          // Wkf
  const short8* wp1 = (const short8*)((const unsigned short*)(ws + OFF_PACK) + 65536);  // W1a

  // kw partial: wave w covers cols [w*64, w*64+64) of row l
  {
    float part = 0.f;
    const unsigned short* trow = XS + l * LDH + w * 64;
#pragma unroll
    for (int j8 = 0; j8 < 8; ++j8) {
      short8 tv = *(const short8*)(trow + j8 * 8);
#pragma unroll
      for (int j = 0; j < 8; ++j)
        part = fmaf(b2f((unsigned short)tv[j]), ws[OFF_WK1 + w * 64 + j8 * 8 + j], part);
    }
    kwbuf[l * 4 + w] = part;
  }

  floatx4 acc1[4][4], acc2[4][4];
  mfma_gemm4(XS, wp0, nullptr, acc1, l, w);          // kpw = X @ Wkf
  mfma_gemm4(XS, wp1, ws + OFF_CB1, acc2, l, w);     // xw1 = X @ W1a + cb1
  __syncthreads();   // all XS reads + kwbuf writes done

  if (tid < 64) {
    float s = kwbuf[tid * 4] + kwbuf[tid * 4 + 1] + kwbuf[tid * 4 + 2] + kwbuf[tid * 4 + 3]
            + ws[OFF_CKW];
    kw_c[((size_t)(tt * 16 + (tid >> 2)) * 64 + b) * 4 + (tid & 3)] = s;
  }

  acc_to_lds(XS, acc1, l, w);
  __syncthreads();
  lds_to_global_bf16(XS, kpw_c, b, tt, tid);
  __syncthreads();
  acc_to_lds(XS, acc2, l, w);
  __syncthreads();
  lds_to_global_bf16(XS, xw1_c, b, tt, tid);
}

// ---------------------------------------------------------------------------
__device__ __forceinline__ float wave_reduce_sum(float x) {
#define DPPSTEP(ctrl, rmask)                                                   \
  {                                                                            \
    int _s = __builtin_amdgcn_update_dpp(0, __builtin_bit_cast(int, x),        \
                                         (ctrl), (rmask), 0xf, true);          \
    x += __builtin_bit_cast(float, _s);                                        \
  }
  DPPSTEP(0x111, 0xf)   // row_shr:1
  DPPSTEP(0x112, 0xf)   // row_shr:2
  DPPSTEP(0x114, 0xf)   // row_shr:4
  DPPSTEP(0x118, 0xf)   // row_shr:8
  DPPSTEP(0x142, 0xa)   // row_bcast15
  DPPSTEP(0x143, 0xc)   // row_bcast31
#undef DPPSTEP
  return __builtin_bit_cast(float, __builtin_amdgcn_readlane(__builtin_bit_cast(int, x), 63));
}

__device__ __forceinline__ float tanh_fast(float y) {
  float ex = __expf(2.f * y);
  return 1.f - 2.f * __builtin_amdgcn_rcpf(ex + 1.f);
}

// ---------------------------------------------------------------------------
// seq v2: 256 blocks, one (b,i) chain each. Wave 0 computes (depth-8 reg
// pipeline); waves 1-3 prefetch the +16-step window into this CU's L1/L2,
// paced by raw s_barrier every 8 steps (timing only, no data exchange).
// ---------------------------------------------------------------------------
__global__ __launch_bounds__(256, 1) void seq_kernel(
    const unsigned short* __restrict__ xw1_c, const unsigned short* __restrict__ kpw_c,
    const float* __restrict__ kw_c, float* __restrict__ ws,
    float* __restrict__ relu_u, int t0, int n)
{
  int b = blockIdx.x & 63;
  int i = blockIdx.x >> 6;
  int tid = threadIdx.x;
  int wv = tid >> 6, l = tid & 63;
  int ngroups = n >> 3;   // n is a multiple of 16

  if (wv == 0) {
    float4 v2v = ((const float4*)(ws + OFF_V2))[l];
    float c2 = ws[OFF_C2];
    float qw = ws[OFF_QW + b * 4 + i];

    const ushort4* xw = (const ushort4*)xw1_c;
    const ushort4* kp = (const ushort4*)kpw_c;

    struct Slot { ushort4 x, k0, k1, k2, k3; float4 kw; };

    auto load = [&](Slot& s, int tc) {
      size_t rb_ = (size_t)(tc * 64 + b) * 4;
      s.x  = xw[(rb_ + i) * 64 + l];
      s.k0 = kp[(rb_ + 0) * 64 + l];
      s.k1 = kp[(rb_ + 1) * 64 + l];
      s.k2 = kp[(rb_ + 2) * 64 + l];
      s.k3 = kp[(rb_ + 3) * 64 + l];
      s.kw = *(const float4*)&kw_c[rb_];
    };

    auto step = [&](Slot& s, int t) {
      float e0 = tanh_fast(qw + s.kw.x);
      float e1 = tanh_fast(qw + s.kw.y);
      float e2 = tanh_fast(qw + s.kw.z);
      float e3 = tanh_fast(qw + s.kw.w);
      float q0 = __expf(e0), q1 = __expf(e1), q2 = __expf(e2), q3 = __expf(e3);
      float inv = __builtin_amdgcn_rcpf(q0 + q1 + q2 + q3);
      float4 K0 = {b2f(s.k0.x), b2f(s.k0.y), b2f(s.k0.z), b2f(s.k0.w)};
      float4 K1 = {b2f(s.k1.x), b2f(s.k1.y), b2f(s.k1.z), b2f(s.k1.w)};
      float4 K2 = {b2f(s.k2.x), b2f(s.k2.y), b2f(s.k2.z), b2f(s.k2.w)};
      float4 K3 = {b2f(s.k3.x), b2f(s.k3.y), b2f(s.k3.z), b2f(s.k3.w)};
      float4 X  = {b2f(s.x.x), b2f(s.x.y), b2f(s.x.z), b2f(s.x.w)};
      float4 a;
      a.x = fmaf(q0, K0.x, fmaf(q1, K1.x, fmaf(q2, K2.x, q3 * K3.x)));
      a.y = fmaf(q0, K0.y, fmaf(q1, K1.y, fmaf(q2, K2.y, q3 * K3.y)));
      a.z = fmaf(q0, K0.z, fmaf(q1, K1.z, fmaf(q2, K2.z, q3 * K3.z)));
      a.w = fmaf(q0, K0.w, fmaf(q1, K1.w, fmaf(q2, K2.w, q3 * K3.w)));
      float4 u;
      u.x = fmaf(a.x, inv, X.x); u.y = fmaf(a.y, inv, X.y);
      u.z = fmaf(a.z, inv, X.z); u.w = fmaf(a.w, inv, X.w);
      float4 r;
      r.x = fmaxf(u.x, 0.f); r.y = fmaxf(u.y, 0.f);
      r.z = fmaxf(u.z, 0.f); r.w = fmaxf(u.w, 0.f);
      float d = fmaf(r.x, v2v.x, fmaf(r.y, v2v.y, fmaf(r.z, v2v.z, r.w * v2v.w)));
      qw = wave_reduce_sum(d) + c2;
      if (t0 + t == SS - 1)
        *(float4*)&relu_u[(size_t)(b * 4 + i) * 256 + l * 4] = r;
    };

    Slot s[8];
#pragma unroll
    for (int j = 0; j < 8; ++j) load(s[j], j < n ? j : n - 1);

    for (int g = 0; g < ngroups; ++g) {
      int t = g * 8;
#pragma unroll
      for (int j = 0; j < 8; ++j) {
        step(s[j], t + j);
        int nt = t + 8 + j;
        load(s[j], nt < n ? nt : n - 1);
      }
      __builtin_amdgcn_s_barrier();
    }
    if (l == 0) ws[OFF_QW + b * 4 + i] = qw;
  } else {
    // prefetch waves: 9 rotating slots; consume previous group's slots first
    float4 f4[9];
    float4 sacc = {0.f, 0.f, 0.f, 0.f};
#pragma unroll
    for (int q = 0; q < 9; ++q) f4[q] = (float4){0.f, 0.f, 0.f, 0.f};

    for (int g = 0; g < ngroups; ++g) {
#pragma unroll
      for (int q = 0; q < 9; ++q) {
        sacc.x += f4[q].x; sacc.y += f4[q].y;
        sacc.z += f4[q].z; sacc.w += f4[q].w;
      }
      int tbase = g * 8 + 16;   // lookahead
#pragma unroll
      for (int tl = 0; tl < 3; ++tl) {
        int tloc = (wv - 1) + 3 * tl; if (tloc > 7) tloc = 7;
        int t = tbase + tloc; if (t > n - 1) t = n - 1;
        size_t rb_ = (size_t)(t * 64 + b) * 4;
        const float4* kpb = (const float4*)(kpw_c + rb_ * 256);  // 4 rows = 2KB
        f4[tl * 3 + 0] = kpb[l];
        f4[tl * 3 + 1] = kpb[64 + l];
        const float4* xwb = (const float4*)(xw1_c + (rb_ + i) * 256);
        const float4* kwb = (const float4*)(kw_c + rb_);
        f4[tl * 3 + 2] = (l < 32) ? xwb[l] : kwb[0];
      }
      __builtin_amdgcn_s_barrier();
    }
    float z = sacc.x + sacc.y + sacc.z + sacc.w;
    asm volatile("" :: "v"(z));
  }
}

// ---------------------------------------------------------------------------
__global__ __launch_bounds__(256) void final_hidden_kernel(
    const float* __restrict__ relu_u, const float* __restrict__ W2,
    const float* __restrict__ b2, float* __restrict__ out)
{
  __shared__ float rs[256];
  int row = blockIdx.x;
  int tid = threadIdx.x;
  rs[tid] = relu_u[(size_t)row * 256 + tid];
  __syncthreads();
  float acc = b2[tid];
  for (int k = 0; k < 256; ++k) acc = fmaf(rs[k], W2[k * 256 + tid], acc);
  out[192 + (size_t)row * 256 + tid] = acc;
}

__global__ __launch_bounds__(256) void final_logits_kernel(
    const float* __restrict__ hf, const float* __restrict__ Wo,
    const float* __restrict__ bo, float* __restrict__ outp)
{
  __shared__ float r0[256], r1[256], r2[256];
  int b = blockIdx.x;
  int tid = threadIdx.x;
  float a0 = 0.f, a1 = 0.f, a2 = 0.f;
  for (int k = tid; k < 1024; k += 256) {
    float h = hf[(size_t)b * 1024 + k];
    a0 = fmaf(h, Wo[k * 3 + 0], a0);
    a1 = fmaf(h, Wo[k * 3 + 1], a1);
    a2 = fmaf(h, Wo[k * 3 + 2], a2);
  }
  r0[tid] = a0; r1[tid] = a1; r2[tid] = a2;
  __syncthreads();
  for (int s = 128; s; s >>= 1) {
    if (tid < s) { r0[tid] += r0[tid + s]; r1[tid] += r1[tid + s]; r2[tid] += r2[tid + s]; }
    __syncthreads();
  }
  if (tid == 0) {
    float l0 = r0[0] + bo[0], l1 = r1[0] + bo[1], l2 = r2[0] + bo[2];
    float m = fmaxf(l0, fmaxf(l1, l2));
    float lse = m + logf(expf(l0 - m) + expf(l1 - m) + expf(l2 - m));
    outp[b * 3 + 0] = l0 - lse;
    outp[b * 3 + 1] = l1 - lse;
    outp[b * 3 + 2] = l2 - lse;
  }
}

// ---------------------------------------------------------------------------
extern "C" void kernel_launch(void* const* d_in, const int* in_sizes, int n_in,
                              void* d_out, int out_size, void* d_ws, size_t ws_size,
                              hipStream_t stream)
{
  const float* x     = (const float*)d_in[0];
  const float* Wk    = (const float*)d_in[1];
  const float* bk    = (const float*)d_in[2];
  const float* Wq    = (const float*)d_in[3];
  const float* bq    = (const float*)d_in[4];
  const float* w_mlp = (const float*)d_in[5];
  const float* Wproj = (const float*)d_in[6];
  const float* bproj = (const float*)d_in[7];
  const float* W1    = (const float*)d_in[8];
  const float* b1    = (const float*)d_in[9];
  const float* W2    = (const float*)d_in[10];
  const float* b2    = (const float*)d_in[11];
  const float* Wo    = (const float*)d_in[12];
  const float* bo    = (const float*)d_in[13];
  float* out = (float*)d_out;
  float* ws  = (float*)d_ws;

  float* ru = ws + OFF_RU;
  const long per_t = 256 + 65536;   // floats per timestep (kw fp32 + 2 bf16 tiles)

  long ws_floats = (long)(ws_size / 4);
  long avail = ws_floats - (long)OFF_CH;

  // full-sequence materialization if it fits (~136 MB); else chunk
  int Tc = SS;
  while (Tc > 16 && (long)Tc * per_t > avail) Tc -= 16;

  float* kw_c = ws + OFF_CH;
  unsigned short* xw1_c = (unsigned short*)(kw_c + (size_t)Tc * 256);
  unsigned short* kpw_c = xw1_c + (size_t)Tc * 65536;

  initA_kernel<<<258, 256, 0, stream>>>(Wproj, W1, bk, bproj, Wq, w_mlp, ws);
  initB_kernel<<<259, 256, 0, stream>>>(Wk, W1, b1, W2, b2, bq, bk, w_mlp, ws);
  initC_kernel<<<512, 256, 0, stream>>>(W1, ws);

  for (int t0 = 0; t0 < SS; t0 += Tc) {
    int n = (SS - t0) < Tc ? (SS - t0) : Tc;
    pre_kernel<<<64 * (n / 16), 256, 0, stream>>>(x, ws, kw_c, xw1_c, kpw_c, t0);
    seq_kernel<<<256, 256, 0, stream>>>(xw1_c, kpw_c, kw_c, ws, ru, t0, n);
  }

  final_hidden_kernel<<<BB * NHH, 256, 0, stream>>>(ru, W2, b2, out);
  final_logits_kernel<<<BB, 256, 0, stream>>>(out + 192, Wo, bo, out);
}

// Round 7
// 447.783 us; speedup vs baseline: 1.0413x; 1.0413x over previous
//
#include <hip/hip_runtime.h>
#include <hip/hip_bf16.h>
#include <math.h>

#define BB   64
#define SS   512
#define NHH  4
#define DD   256
#define HH   256
#define LDH  264   // bf16 LDS row stride (halfwords); 528B = 16B-aligned

typedef __attribute__((ext_vector_type(8))) short  short8;
typedef __attribute__((ext_vector_type(4))) float  floatx4;

// ---------------------------------------------------------------------------
// ws layout (floats): unchanged from R4-R6.
// ---------------------------------------------------------------------------
#define OFF_V2     0
#define OFF_CB1    256
#define OFF_C2     512
#define OFF_CKW    513
#define OFF_QW     768
#define OFF_WK1    1024
#define OFF_BKP    1280
#define OFF_VT     1536
#define OFF_RU     1792
#define OFF_WFUSE  67328
#define OFF_WKF    132864
#define OFF_PACK   198400
#define OFF_CH     263936

__device__ __forceinline__ unsigned short f2b(float f) {
  __hip_bfloat16 h = __float2bfloat16(f);
  return __builtin_bit_cast(unsigned short, h);
}
__device__ __forceinline__ float b2f(unsigned short u) {
  unsigned v = (unsigned)u << 16;
  return __builtin_bit_cast(float, v);
}

// ---------------------------------------------------------------------------
// initA: blocks 0..255: Wfuse = Wproj @ W1b ; 256: bkp ; 257: vtmp = Wq@w2
// ---------------------------------------------------------------------------
__global__ __launch_bounds__(256) void initA_kernel(
    const float* __restrict__ Wproj, const float* __restrict__ W1,
    const float* __restrict__ bk, const float* __restrict__ bproj,
    const float* __restrict__ Wq, const float* __restrict__ w_mlp,
    float* __restrict__ ws)
{
  int tid = threadIdx.x;
  int bx = blockIdx.x;
  const float* W1b = W1 + 256 * 256;
  if (bx < 256) {
    __shared__ float row[256];
    row[tid] = Wproj[bx * 256 + tid];
    __syncthreads();
    float acc = 0.f;
#pragma unroll 8
    for (int k = 0; k < 256; ++k)
      acc = fmaf(row[k], W1b[k * 256 + tid], acc);
    ws[OFF_WFUSE + bx * 256 + tid] = acc;
  } else if (bx == 256) {
    float acc = bproj[tid];
#pragma unroll 8
    for (int k = 0; k < 256; ++k)
      acc = fmaf(bk[k], Wproj[k * 256 + tid], acc);
    ws[OFF_BKP + tid] = acc;
  } else {
    const float4* Wq4 = (const float4*)(Wq + tid * 256);
    const float4* w24 = (const float4*)(w_mlp + 256);
    float a = 0.f;
    for (int k = 0; k < 64; ++k) {
      float4 wv = Wq4[k], xv = w24[k];
      a = fmaf(wv.x, xv.x, fmaf(wv.y, xv.y, fmaf(wv.z, xv.z, fmaf(wv.w, xv.w, a))));
    }
    ws[OFF_VT + tid] = a;
  }
}

// ---------------------------------------------------------------------------
// initB: blocks 0..255: Wkf = Wk@Wfuse ; 256: cb1 ; 257: v2,c2,ckw,qw ; 258: wk1
// ---------------------------------------------------------------------------
__global__ __launch_bounds__(256) void initB_kernel(
    const float* __restrict__ Wk, const float* __restrict__ W1,
    const float* __restrict__ b1, const float* __restrict__ W2,
    const float* __restrict__ b2, const float* __restrict__ bq,
    const float* __restrict__ bk, const float* __restrict__ w_mlp,
    float* __restrict__ ws)
{
  int tid = threadIdx.x;
  int bx = blockIdx.x;
  if (bx < 256) {
    __shared__ float row[256];
    row[tid] = Wk[bx * 256 + tid];
    __syncthreads();
    float acc = 0.f;
    const float* Wf = ws + OFF_WFUSE;
#pragma unroll 8
    for (int k = 0; k < 256; ++k)
      acc = fmaf(row[k], Wf[k * 256 + tid], acc);
    ws[OFF_WKF + bx * 256 + tid] = acc;
  } else if (bx == 256) {
    const float* W1b = W1 + 256 * 256;
    float acc = b1[tid];
#pragma unroll 8
    for (int k = 0; k < 256; ++k)
      acc = fmaf(ws[OFF_BKP + k], W1b[k * 256 + tid], acc);
    ws[OFF_CB1 + tid] = acc;
  } else if (bx == 257) {
    __shared__ float red[256];
    {
      const float4* W24 = (const float4*)(W2 + tid * 256);
      const float4* v4  = (const float4*)(ws + OFF_VT);
      float a = 0.f;
      for (int k = 0; k < 64; ++k) {
        float4 wv = W24[k], xv = v4[k];
        a = fmaf(wv.x, xv.x, fmaf(wv.y, xv.y, fmaf(wv.z, xv.z, fmaf(wv.w, xv.w, a))));
      }
      ws[OFF_V2 + tid] = a;
    }
    red[tid] = bq[tid] * w_mlp[256 + tid];
    __syncthreads();
    for (int s = 128; s; s >>= 1) { if (tid < s) red[tid] += red[tid + s]; __syncthreads(); }
    float s2 = red[0];
    __syncthreads();
    ws[OFF_QW + tid] = s2;
    red[tid] = b2[tid] * ws[OFF_VT + tid];
    __syncthreads();
    for (int s = 128; s; s >>= 1) { if (tid < s) red[tid] += red[tid + s]; __syncthreads(); }
    if (tid == 0) ws[OFF_C2] = red[0] + s2;
    __syncthreads();
    red[tid] = bk[tid] * w_mlp[tid];
    __syncthreads();
    for (int s = 128; s; s >>= 1) { if (tid < s) red[tid] += red[tid + s]; __syncthreads(); }
    if (tid == 0) ws[OFF_CKW] = red[0];
  } else {
    const float4* Wk4 = (const float4*)(Wk + tid * 256);
    const float4* w14 = (const float4*)(w_mlp);
    float a = 0.f;
    for (int k = 0; k < 64; ++k) {
      float4 wv = Wk4[k], xv = w14[k];
      a = fmaf(wv.x, xv.x, fmaf(wv.y, xv.y, fmaf(wv.z, xv.z, fmaf(wv.w, xv.w, a))));
    }
    ws[OFF_WK1 + tid] = a;
  }
}

// ---------------------------------------------------------------------------
// initC: pack Wkf (mat0, from ws fp32) and W1a (mat1) into MFMA B-frag bf16
// ---------------------------------------------------------------------------
__global__ __launch_bounds__(256) void initC_kernel(
    const float* __restrict__ W1, float* __restrict__ ws)
{
  int idx = blockIdx.x * 256 + threadIdx.x;   // 0..131071
  int mat = idx >> 16;
  int rem = idx & 65535;
  int j    = rem & 7;
  int lane = (rem >> 3) & 63;
  int ks   = (rem >> 9) & 7;
  int pan  = rem >> 12;
  int k = ks * 32 + ((lane >> 4) << 3) + j;
  int n = pan * 16 + (lane & 15);
  float v = (mat == 0) ? ws[OFF_WKF + k * 256 + n] : W1[k * 256 + n];
  ((unsigned short*)(ws + OFF_PACK))[idx] = f2b(v);
}

// ---------------------------------------------------------------------------
// 64x256 (K=256) bf16 MFMA GEMM, 4x B-reuse
// ---------------------------------------------------------------------------
__device__ __forceinline__ void mfma_gemm4(
    const unsigned short* A_lds, const short8* __restrict__ Bp,
    const float* __restrict__ bias, floatx4 acc[4][4], int l, int w)
{
  int col = l & 15, quad = l >> 4;
#pragma unroll
  for (int pp = 0; pp < 4; ++pp) {
    float bv = bias ? bias[(w * 4 + pp) * 16 + col] : 0.f;
#pragma unroll
    for (int mf = 0; mf < 4; ++mf)
      acc[mf][pp] = (floatx4){bv, bv, bv, bv};
  }
  const short8* Bb = Bp + (size_t)(w * 4) * 512 + l;
  short8 bb[3][4];
#pragma unroll
  for (int pp = 0; pp < 4; ++pp) bb[0][pp] = Bb[pp * 512];
#pragma unroll
  for (int pp = 0; pp < 4; ++pp) bb[1][pp] = Bb[pp * 512 + 64];
#pragma unroll
  for (int kb = 0; kb < 8; ++kb) {
    if (kb + 2 < 8) {
#pragma unroll
      for (int pp = 0; pp < 4; ++pp)
        bb[(kb + 2) % 3][pp] = Bb[pp * 512 + (kb + 2) * 64];
    }
    short8 aa[4];
#pragma unroll
    for (int mf = 0; mf < 4; ++mf)
      aa[mf] = *(const short8*)(A_lds + (mf * 16 + col) * LDH + kb * 32 + quad * 8);
#pragma unroll
    for (int mf = 0; mf < 4; ++mf)
#pragma unroll
      for (int pp = 0; pp < 4; ++pp)
        acc[mf][pp] = __builtin_amdgcn_mfma_f32_16x16x32_bf16(
            aa[mf], bb[kb % 3][pp], acc[mf][pp], 0, 0, 0);
  }
}

// acc -> bf16 LDS tile
__device__ __forceinline__ void acc_to_lds(
    unsigned short* D, const floatx4 acc[4][4], int l, int w)
{
  int col = l & 15, quad = l >> 4;
#pragma unroll
  for (int mf = 0; mf < 4; ++mf)
#pragma unroll
    for (int pp = 0; pp < 4; ++pp)
#pragma unroll
      for (int r = 0; r < 4; ++r)
        D[(mf * 16 + quad * 4 + r) * LDH + (w * 4 + pp) * 16 + col] = f2b(acc[mf][pp][r]);
}

// LDS bf16 tile -> global, coalesced 16B chunks; layout [t][b][head][256]
__device__ __forceinline__ void lds_to_global_bf16(
    const unsigned short* S, unsigned short* __restrict__ g, int b, int tt, int tid)
{
#pragma unroll
  for (int it = 0; it < 8; ++it) {
    int u8 = it * 256 + tid;        // 16B chunk id, 0..2047
    int r = u8 >> 5;                // row 0..63
    int c8 = u8 & 31;               // chunk within row
    int t = tt * 16 + (r >> 2), head = r & 3;
    float4 v = *(const float4*)&S[r * LDH + c8 * 8];
    *(float4*)&g[(((size_t)t * 64 + b) * 4 + head) * 256 + c8 * 8] = v;
  }
}

// ---------------------------------------------------------------------------
// pre: one block per (b, tt). Single live acc; coalesced LDS epilogue via TS.
// ---------------------------------------------------------------------------
__global__ __launch_bounds__(256, 2) void pre_kernel(
    const float* __restrict__ x, const float* __restrict__ ws,
    float* __restrict__ kw_c, unsigned short* __restrict__ xw1_c,
    unsigned short* __restrict__ kpw_c, int t0)
{
  __shared__ float kwbuf[256];
  __shared__ __align__(16) unsigned short XS[64 * LDH];
  __shared__ __align__(16) unsigned short TS[64 * LDH];

  int b  = blockIdx.x & 63;
  int tt = blockIdx.x >> 6;
  int tid = threadIdx.x;
  int l = tid & 63, w = tid >> 6;

  const float4* xsrc = (const float4*)(x + (size_t)(b * SS + t0 + tt * 16) * NHH * DD);
#pragma unroll
  for (int it = 0; it < 16; ++it) {
    int f4 = it * 256 + tid;
    int r = f4 >> 6, c4 = f4 & 63;
    float4 v = xsrc[f4];
    ushort4 h;
    h.x = f2b(v.x); h.y = f2b(v.y); h.z = f2b(v.z); h.w = f2b(v.w);
    *(ushort4*)&XS[r * LDH + c4 * 4] = h;
  }
  __syncthreads();

  const short8* wp0 = (const short8*)((const unsigned short*)(ws + OFF_PACK));          // Wkf
  const short8* wp1 = (const short8*)((const unsigned short*)(ws + OFF_PACK) + 65536);  // W1a

  // kw partial: wave w covers cols [w*64, w*64+64) of row l
  {
    float part = 0.f;
    const unsigned short* trow = XS + l * LDH + w * 64;
#pragma unroll
    for (int j8 = 0; j8 < 8; ++j8) {
      short8 tv = *(const short8*)(trow + j8 * 8);
#pragma unroll
      for (int j = 0; j < 8; ++j)
        part = fmaf(b2f((unsigned short)tv[j]), ws[OFF_WK1 + w * 64 + j8 * 8 + j], part);
    }
    kwbuf[l * 4 + w] = part;
  }

  floatx4 acc[4][4];

  // GEMM 1: kpw = X @ Wkf -> TS -> global (coalesced)
  mfma_gemm4(XS, wp0, nullptr, acc, l, w);
  acc_to_lds(TS, acc, l, w);
  __syncthreads();                     // TS + kwbuf visible
  if (tid < 64) {
    float s = kwbuf[tid * 4] + kwbuf[tid * 4 + 1] + kwbuf[tid * 4 + 2] + kwbuf[tid * 4 + 3]
            + ws[OFF_CKW];
    kw_c[((size_t)(tt * 16 + (tid >> 2)) * 64 + b) * 4 + (tid & 3)] = s;
  }
  lds_to_global_bf16(TS, kpw_c, b, tt, tid);

  // GEMM 2: xw1 = X @ W1a + cb1 -> TS -> global
  mfma_gemm4(XS, wp1, ws + OFF_CB1, acc, l, w);
  __syncthreads();                     // TS copy reads done
  acc_to_lds(TS, acc, l, w);
  __syncthreads();
  lds_to_global_bf16(TS, xw1_c, b, tt, tid);
}

// ---------------------------------------------------------------------------
__device__ __forceinline__ float wave_reduce_sum(float x) {
#define DPPSTEP(ctrl, rmask)                                                   \
  {                                                                            \
    int _s = __builtin_amdgcn_update_dpp(0, __builtin_bit_cast(int, x),        \
                                         (ctrl), (rmask), 0xf, true);          \
    x += __builtin_bit_cast(float, _s);                                        \
  }
  DPPSTEP(0x111, 0xf)   // row_shr:1
  DPPSTEP(0x112, 0xf)   // row_shr:2
  DPPSTEP(0x114, 0xf)   // row_shr:4
  DPPSTEP(0x118, 0xf)   // row_shr:8
  DPPSTEP(0x142, 0xa)   // row_bcast15
  DPPSTEP(0x143, 0xc)   // row_bcast31
#undef DPPSTEP
  return __builtin_bit_cast(float, __builtin_amdgcn_readlane(__builtin_bit_cast(int, x), 63));
}

__device__ __forceinline__ float tanh_fast(float y) {
  float ex = __expf(2.f * y);
  return 1.f - 2.f * __builtin_amdgcn_rcpf(ex + 1.f);
}

// ---------------------------------------------------------------------------
// seq v3: 256 blocks, one (b,i) chain each. Waves 1-3 = producers: global bf16
// -> fp32 -> LDS ring (24 slots x 5KB, 2-group lookahead). Wave 0 = consumer:
// ds_read ping-pong, pure fp32 chain. __syncthreads paces 8-step groups.
// ---------------------------------------------------------------------------
#define RING  24
#define SLOT  1284   // floats: kp[4][256] | x[256] | kw[4]

__global__ __launch_bounds__(256, 1) void seq_kernel(
    const unsigned short* __restrict__ xw1_c, const unsigned short* __restrict__ kpw_c,
    const float* __restrict__ kw_c, float* __restrict__ ws,
    float* __restrict__ relu_u, int t0, int n)
{
  __shared__ float ring[RING * SLOT];
  int b = blockIdx.x & 63;
  int i = blockIdx.x >> 6;
  int tid = threadIdx.x;
  int wv = tid >> 6, l = tid & 63;
  int ngroups = n >> 3;    // n is a multiple of 16

  if (wv != 0) {
    // ---- producers ----
    int tsel = wv - 1;     // 0,1,2
    auto fill = [&](int t) {
      if (t >= n) return;
      size_t rb = (size_t)(t * 64 + b) * 4;
      float* slot = ring + (t % RING) * SLOT;
      ushort4 h0 = ((const ushort4*)(kpw_c + (rb + 0) * 256))[l];
      ushort4 h1 = ((const ushort4*)(kpw_c + (rb + 1) * 256))[l];
      ushort4 h2 = ((const ushort4*)(kpw_c + (rb + 2) * 256))[l];
      ushort4 h3 = ((const ushort4*)(kpw_c + (rb + 3) * 256))[l];
      ushort4 hx = ((const ushort4*)(xw1_c + (rb + i) * 256))[l];
      float4 kwv = *(const float4*)(kw_c + rb);   // uniform; cheap
      *(float4*)&slot[0 * 256 + l * 4] = (float4){b2f(h0.x), b2f(h0.y), b2f(h0.z), b2f(h0.w)};
      *(float4*)&slot[1 * 256 + l * 4] = (float4){b2f(h1.x), b2f(h1.y), b2f(h1.z), b2f(h1.w)};
      *(float4*)&slot[2 * 256 + l * 4] = (float4){b2f(h2.x), b2f(h2.y), b2f(h2.z), b2f(h2.w)};
      *(float4*)&slot[3 * 256 + l * 4] = (float4){b2f(h3.x), b2f(h3.y), b2f(h3.z), b2f(h3.w)};
      *(float4*)&slot[4 * 256 + l * 4] = (float4){b2f(hx.x), b2f(hx.y), b2f(hx.z), b2f(hx.w)};
      if (l == 0) *(float4*)&slot[1280] = kwv;
    };
    // priming: groups 0,1 (steps 0..15)
    for (int tl = tsel; tl < 16; tl += 3) fill(tl);
    __syncthreads();
    for (int g = 0; g < ngroups; ++g) {
      int base = (g + 2) * 8;
      fill(base + tsel);
      fill(base + tsel + 3);
      if (tsel < 2) fill(base + tsel + 6);
      __syncthreads();
    }
  } else {
    // ---- consumer ----
    float4 v2v = ((const float4*)(ws + OFF_V2))[l];
    float c2 = ws[OFF_C2];
    float qw = ws[OFF_QW + b * 4 + i];

    float4 K0a, K1a, K2a, K3a, Xa, KWa;
    float4 K0b, K1b, K2b, K3b, Xb, KWb;

    auto rdA = [&](int t) {
      const float* slot = ring + (t % RING) * SLOT;
      K0a = *(const float4*)&slot[0 * 256 + l * 4];
      K1a = *(const float4*)&slot[1 * 256 + l * 4];
      K2a = *(const float4*)&slot[2 * 256 + l * 4];
      K3a = *(const float4*)&slot[3 * 256 + l * 4];
      Xa  = *(const float4*)&slot[4 * 256 + l * 4];
      KWa = *(const float4*)&slot[1280];
    };
    auto rdB = [&](int t) {
      const float* slot = ring + (t % RING) * SLOT;
      K0b = *(const float4*)&slot[0 * 256 + l * 4];
      K1b = *(const float4*)&slot[1 * 256 + l * 4];
      K2b = *(const float4*)&slot[2 * 256 + l * 4];
      K3b = *(const float4*)&slot[3 * 256 + l * 4];
      Xb  = *(const float4*)&slot[4 * 256 + l * 4];
      KWb = *(const float4*)&slot[1280];
    };

    auto step = [&](const float4& K0, const float4& K1, const float4& K2,
                    const float4& K3, const float4& X, const float4& KW, int t) {
      float e0 = tanh_fast(qw + KW.x);
      float e1 = tanh_fast(qw + KW.y);
      float e2 = tanh_fast(qw + KW.z);
      float e3 = tanh_fast(qw + KW.w);
      float q0 = __expf(e0), q1 = __expf(e1), q2 = __expf(e2), q3 = __expf(e3);
      float inv = __builtin_amdgcn_rcpf(q0 + q1 + q2 + q3);
      float4 a;
      a.x = fmaf(q0, K0.x, fmaf(q1, K1.x, fmaf(q2, K2.x, q3 * K3.x)));
      a.y = fmaf(q0, K0.y, fmaf(q1, K1.y, fmaf(q2, K2.y, q3 * K3.y)));
      a.z = fmaf(q0, K0.z, fmaf(q1, K1.z, fmaf(q2, K2.z, q3 * K3.z)));
      a.w = fmaf(q0, K0.w, fmaf(q1, K1.w, fmaf(q2, K2.w, q3 * K3.w)));
      float4 u;
      u.x = fmaf(a.x, inv, X.x); u.y = fmaf(a.y, inv, X.y);
      u.z = fmaf(a.z, inv, X.z); u.w = fmaf(a.w, inv, X.w);
      float4 r;
      r.x = fmaxf(u.x, 0.f); r.y = fmaxf(u.y, 0.f);
      r.z = fmaxf(u.z, 0.f); r.w = fmaxf(u.w, 0.f);
      float d = fmaf(r.x, v2v.x, fmaf(r.y, v2v.y, fmaf(r.z, v2v.z, r.w * v2v.w)));
      qw = wave_reduce_sum(d) + c2;
      if (t0 + t == SS - 1)
        *(float4*)&relu_u[(size_t)(b * 4 + i) * 256 + l * 4] = r;
    };

    __syncthreads();   // priming barrier
    rdA(0);
    for (int g = 0; g < ngroups; ++g) {
      int t = g * 8;
      int c1 = t + 1, c2i = t + 2, c3 = t + 3, c4 = t + 4;
      int c5 = t + 5, c6 = t + 6, c7 = t + 7;
      int c8 = (t + 8 < n) ? t + 8 : n - 1;
      rdB(c1);  step(K0a, K1a, K2a, K3a, Xa, KWa, t);
      rdA(c2i); step(K0b, K1b, K2b, K3b, Xb, KWb, t + 1);
      rdB(c3);  step(K0a, K1a, K2a, K3a, Xa, KWa, t + 2);
      rdA(c4);  step(K0b, K1b, K2b, K3b, Xb, KWb, t + 3);
      rdB(c5);  step(K0a, K1a, K2a, K3a, Xa, KWa, t + 4);
      rdA(c6);  step(K0b, K1b, K2b, K3b, Xb, KWb, t + 5);
      rdB(c7);  step(K0a, K1a, K2a, K3a, Xa, KWa, t + 6);
      rdA(c8);  step(K0b, K1b, K2b, K3b, Xb, KWb, t + 7);
      __syncthreads();
    }
    if (l == 0) ws[OFF_QW + b * 4 + i] = qw;
  }
}

// ---------------------------------------------------------------------------
__global__ __launch_bounds__(256) void final_hidden_kernel(
    const float* __restrict__ relu_u, const float* __restrict__ W2,
    const float* __restrict__ b2, float* __restrict__ out)
{
  __shared__ float rs[256];
  int row = blockIdx.x;
  int tid = threadIdx.x;
  rs[tid] = relu_u[(size_t)row * 256 + tid];
  __syncthreads();
  float acc = b2[tid];
  for (int k = 0; k < 256; ++k) acc = fmaf(rs[k], W2[k * 256 + tid], acc);
  out[192 + (size_t)row * 256 + tid] = acc;
}

__global__ __launch_bounds__(256) void final_logits_kernel(
    const float* __restrict__ hf, const float* __restrict__ Wo,
    const float* __restrict__ bo, float* __restrict__ outp)
{
  __shared__ float r0[256], r1[256], r2[256];
  int b = blockIdx.x;
  int tid = threadIdx.x;
  float a0 = 0.f, a1 = 0.f, a2 = 0.f;
  for (int k = tid; k < 1024; k += 256) {
    float h = hf[(size_t)b * 1024 + k];
    a0 = fmaf(h, Wo[k * 3 + 0], a0);
    a1 = fmaf(h, Wo[k * 3 + 1], a1);
    a2 = fmaf(h, Wo[k * 3 + 2], a2);
  }
  r0[tid] = a0; r1[tid] = a1; r2[tid] = a2;
  __syncthreads();
  for (int s = 128; s; s >>= 1) {
    if (tid < s) { r0[tid] += r0[tid + s]; r1[tid] += r1[tid + s]; r2[tid] += r2[tid + s]; }
    __syncthreads();
  }
  if (tid == 0) {
    float l0 = r0[0] + bo[0], l1 = r1[0] + bo[1], l2 = r2[0] + bo[2];
    float m = fmaxf(l0, fmaxf(l1, l2));
    float lse = m + logf(expf(l0 - m) + expf(l1 - m) + expf(l2 - m));
    outp[b * 3 + 0] = l0 - lse;
    outp[b * 3 + 1] = l1 - lse;
    outp[b * 3 + 2] = l2 - lse;
  }
}

// ---------------------------------------------------------------------------
extern "C" void kernel_launch(void* const* d_in, const int* in_sizes, int n_in,
                              void* d_out, int out_size, void* d_ws, size_t ws_size,
                              hipStream_t stream)
{
  const float* x     = (const float*)d_in[0];
  const float* Wk    = (const float*)d_in[1];
  const float* bk    = (const float*)d_in[2];
  const float* Wq    = (const float*)d_in[3];
  const float* bq    = (const float*)d_in[4];
  const float* w_mlp = (const float*)d_in[5];
  const float* Wproj = (const float*)d_in[6];
  const float* bproj = (const float*)d_in[7];
  const float* W1    = (const float*)d_in[8];
  const float* b1    = (const float*)d_in[9];
  const float* W2    = (const float*)d_in[10];
  const float* b2    = (const float*)d_in[11];
  const float* Wo    = (const float*)d_in[12];
  const float* bo    = (const float*)d_in[13];
  float* out = (float*)d_out;
  float* ws  = (float*)d_ws;

  float* ru = ws + OFF_RU;
  const long per_t = 256 + 65536;   // floats per timestep (kw fp32 + 2 bf16 tiles)

  long ws_floats = (long)(ws_size / 4);
  long avail = ws_floats - (long)OFF_CH;

  // full-sequence materialization if it fits (~136 MB); else chunk
  int Tc = SS;
  while (Tc > 16 && (long)Tc * per_t > avail) Tc -= 16;

  float* kw_c = ws + OFF_CH;
  unsigned short* xw1_c = (unsigned short*)(kw_c + (size_t)Tc * 256);
  unsigned short* kpw_c = xw1_c + (size_t)Tc * 65536;

  initA_kernel<<<258, 256, 0, stream>>>(Wproj, W1, bk, bproj, Wq, w_mlp, ws);
  initB_kernel<<<259, 256, 0, stream>>>(Wk, W1, b1, W2, b2, bq, bk, w_mlp, ws);
  initC_kernel<<<512, 256, 0, stream>>>(W1, ws);

  for (int t0 = 0; t0 < SS; t0 += Tc) {
    int n = (SS - t0) < Tc ? (SS - t0) : Tc;
    pre_kernel<<<64 * (n / 16), 256, 0, stream>>>(x, ws, kw_c, xw1_c, kpw_c, t0);
    seq_kernel<<<256, 256, 0, stream>>>(xw1_c, kpw_c, kw_c, ws, ru, t0, n);
  }

  final_hidden_kernel<<<BB * NHH, 256, 0, stream>>>(ru, W2, b2, out);
  final_logits_kernel<<<BB, 256, 0, stream>>>(out + 192, Wo, bo, out);
}